// Round 6
// baseline (257.740 us; speedup 1.0000x reference)
//
#include <hip/hip_runtime.h>
#include <stdint.h>

#define BATCH 256
#define QN 64
#define HN 2048
#define H2 (HN / 2)   // 1024
#define WPB 4         // waves per block
#define ROWS 16       // rows per wave (1024 waves x 16 = 16384 rows)

typedef float v4f __attribute__((ext_vector_type(4)));
typedef float v2f __attribute__((ext_vector_type(2)));

typedef __attribute__((address_space(3))) uint32_t lds_u32;
typedef __attribute__((address_space(1))) const uint32_t glb_u32;

// Kernel A: factor[k][h] = prod_{j>k} W[k][j][h] * prod_{i<k} W[i][k][h]
__global__ __launch_bounds__(256) void factor_kernel(const float* __restrict__ W,
                                                     float* __restrict__ factor) {
    int idx = blockIdx.x * blockDim.x + threadIdx.x;
    int h2 = idx & (H2 - 1);
    int k  = idx >> 10;
    const v2f* W2 = (const v2f*)W;
    v2f p = {1.f, 1.f};
    #pragma unroll 8
    for (int j = k + 1; j < QN; ++j)
        p *= __builtin_nontemporal_load(&W2[(size_t)(k * QN + j) * H2 + h2]);
    #pragma unroll 8
    for (int i = 0; i < k; ++i)
        p *= __builtin_nontemporal_load(&W2[(size_t)(i * QN + k) * H2 + h2]);
    ((v2f*)factor)[(size_t)k * H2 + h2] = p;   // normal store -> stays in L2
}

// Kernel B: per-wave async pipeline, NO barriers. Each wave owns a private
// 2 x 8 KB LDS double-buffer and streams 16 rows (all same q, factor in regs).
// vmcnt is per-wave, so `s_waitcnt vmcnt(8)` waits exactly for the oldest
// fill while the next row's 8 KB stays in flight. 2 blocks/CU (64 KB LDS)
// -> 8 waves/CU x 8 KB = 64 KB continuously in flight per CU.
__global__ __launch_bounds__(256, 2) void normalize_kernel(const float* __restrict__ x,
                                                           const float* __restrict__ factor,
                                                           float* __restrict__ out) {
    __shared__ float xs[2][WPB][HN];    // 64 KB
    const int t    = threadIdx.x;
    const int wave = t >> 6;
    const int lane = t & 63;
    const int gw   = blockIdx.x * WPB + wave;   // 0..1023
    const int q     = gw & (QN - 1);
    const int bbase = (gw >> 6) * ROWS;         // 16 batch-chunks

    // factor[q] once into registers (compiler inserts its own vmcnt wait)
    const v4f* f4 = (const v4f*)(factor + (size_t)q * HN);
    v4f b[8];
    #pragma unroll
    for (int i = 0; i < 8; ++i) b[i] = f4[lane + 64 * i];

    // issue one row fill: 8 x global_load_lds(16B) into this wave's buffer
    auto issue = [&](int r, int buf) {
        const float* src = x + ((size_t)(bbase + r) * QN + q) * HN + lane * 4;
        float* dst = (float*)&xs[buf][wave][0];
        #pragma unroll
        for (int i = 0; i < 8; ++i)
            __builtin_amdgcn_global_load_lds((glb_u32*)(src + i * 256),
                                             (lds_u32*)(dst + i * 256), 16, 0, 0);
    };

    issue(0, 0);
    issue(1, 1);

    for (int r = 0; r < ROWS; ++r) {
        const int buf = r & 1;
        // queue (oldest->newest): [fill_r, stores_{r-1}, fill_{r+1}]
        // vmcnt(8) leaves only fill_{r+1} outstanding -> fill_r landed.
        asm volatile("s_waitcnt vmcnt(8)" ::: "memory");

        const v4f* s4 = (const v4f*)&xs[buf][wave][0];
        v4f a[8];
        float ss = 0.f;
        #pragma unroll
        for (int i = 0; i < 8; ++i) {
            a[i] = s4[lane + 64 * i] * b[i];
            ss += a[i].x * a[i].x + a[i].y * a[i].y + a[i].z * a[i].z + a[i].w * a[i].w;
        }
        #pragma unroll
        for (int off = 32; off >= 1; off >>= 1)
            ss += __shfl_xor(ss, off, 64);
        float inv = 1.0f / fmaxf(sqrtf(ss), 1e-12f);

        v4f* o4 = (v4f*)(out + ((size_t)(bbase + r) * QN + q) * HN);
        #pragma unroll
        for (int i = 0; i < 8; ++i) {
            v4f yi = a[i] * inv;
            __builtin_nontemporal_store(yi, &o4[lane + 64 * i]);
        }
        if (r + 2 < ROWS) issue(r + 2, buf);   // AFTER stores: keeps vmcnt order
    }
}

extern "C" void kernel_launch(void* const* d_in, const int* in_sizes, int n_in,
                              void* d_out, int out_size, void* d_ws, size_t ws_size,
                              hipStream_t stream) {
    const float* x = (const float*)d_in[0];
    const float* W = (const float*)d_in[1];
    float* out     = (float*)d_out;
    float* factor  = (float*)d_ws;   // QN*HN floats = 512 KB

    factor_kernel<<<(QN * H2) / 256, 256, 0, stream>>>(W, factor);
    normalize_kernel<<<(BATCH * QN) / (WPB * ROWS), 256, 0, stream>>>(x, factor, out);
}